// Round 4
// baseline (833.917 us; speedup 1.0000x reference)
//
#include <hip/hip_runtime.h>
#include <math.h>

// MEASUREMENT ROUND: same CE kernel, but the streaming loop runs 4 rotated
// passes (sum/4) so the dispatch exceeds the harness fill kernels (~324us)
// and lands in rocprof top-5 WITH counters (hbm_gbps / VALUBusy / occupancy).
// pass_start is a runtime arg so the compiler cannot fold the idempotent
// passes into one (addresses differ per pass as far as it can prove).

#define NCLS 32000
#define NROW 4096
#define HALF4 4000   // float4 per half-row
#define HALFN 16000  // floats per half-row

typedef float f4 __attribute__((ext_vector_type(4)));

__device__ __forceinline__ float exp4sum(f4 v) {
    return (__expf(v.x) + __expf(v.y)) + (__expf(v.z) + __expf(v.w));
}

__device__ __forceinline__ f4 ldwrap(const f4* __restrict__ base, int idx) {
    if (idx >= HALF4) idx -= HALF4;  // idx < 2*HALF4 guaranteed by caller
    return __builtin_nontemporal_load(base + idx);
}

// d_ws layout: [0,4096) xt_arr ; [4096,4096+8192) partial sums
__global__ __launch_bounds__(256) void ce_partial_probe(const float* __restrict__ pred,
                                                        const int* __restrict__ target,
                                                        float* __restrict__ ws,
                                                        int pass_start) {
    const int bid = blockIdx.x;
    const int b = bid >> 1;
    const int half = bid & 1;
    const int tid = threadIdx.x;

    const float* row = pred + (size_t)b * NCLS;
    const f4* half4 = reinterpret_cast<const f4*>(row) + half * HALF4;

    const int t = target[b];
    if (tid == 0 && (unsigned)(t - half * HALFN) < (unsigned)HALFN) {
        ws[b] = row[t];
    }

    float s0 = 0.f, s1 = 0.f, s2 = 0.f, s3 = 0.f;
    for (int p = 0; p < 4; ++p) {
        const int start = p * pass_start;  // runtime -> passes not foldable
        int i = tid;
        for (; i + 768 < HALF4; i += 1024) {
            f4 a = ldwrap(half4, i + start);
            f4 c = ldwrap(half4, i + 256 + start);
            f4 d = ldwrap(half4, i + 512 + start);
            f4 e = ldwrap(half4, i + 768 + start);
            s0 += exp4sum(a);
            s1 += exp4sum(c);
            s2 += exp4sum(d);
            s3 += exp4sum(e);
        }
        for (; i < HALF4; i += 256) {
            s0 += exp4sum(ldwrap(half4, i + start));
        }
    }
    float s = ((s0 + s1) + (s2 + s3)) * 0.25f;

    for (int off = 32; off; off >>= 1) s += __shfl_down(s, off, 64);

    __shared__ float ss[4];
    if ((tid & 63) == 0) ss[tid >> 6] = s;
    __syncthreads();
    if (tid == 0) {
        ws[NROW + bid] = (ss[0] + ss[1]) + (ss[2] + ss[3]);
    }
}

__global__ __launch_bounds__(256) void ce_final(const float* __restrict__ ws,
                                                float* __restrict__ out) {
    const float* xt = ws;
    const float* part = ws + NROW;
    float acc = 0.0f;
    for (int b = threadIdx.x; b < NROW; b += 256) {
        float S = part[2 * b] + part[2 * b + 1];
        acc += __logf(S) - xt[b];
    }
    for (int off = 32; off; off >>= 1) acc += __shfl_down(acc, off, 64);
    __shared__ float sacc[4];
    if ((threadIdx.x & 63) == 0) sacc[threadIdx.x >> 6] = acc;
    __syncthreads();
    if (threadIdx.x == 0) {
        out[0] = ((sacc[0] + sacc[1]) + (sacc[2] + sacc[3])) / (float)NROW;
    }
}

extern "C" void kernel_launch(void* const* d_in, const int* in_sizes, int n_in,
                              void* d_out, int out_size, void* d_ws, size_t ws_size,
                              hipStream_t stream) {
    const float* pred = (const float*)d_in[0];
    const int* target = (const int*)d_in[1];
    float* out = (float*)d_out;
    float* ws = (float*)d_ws;

    ce_partial_probe<<<2 * NROW, 256, 0, stream>>>(pred, target, ws, 1000);
    ce_final<<<1, 256, 0, stream>>>(ws, out);
}